// Round 9
// baseline (121.531 us; speedup 1.0000x reference)
//
#include <hip/hip_runtime.h>
#include <hip/hip_bf16.h>

#define B_ 32
#define T_ 4096
#define H_ 512
#define TILE_T 2
#define M_TILE 64    // TILE_T * B_
#define BK 64
#define KSTEPS 8     // H_ / BK
#define NTHREADS 256 // 4 waves; 3 blocks/CU

typedef __attribute__((ext_vector_type(8))) short short8;
typedef __attribute__((ext_vector_type(8))) __bf16 bf16x8;
typedef __attribute__((ext_vector_type(4))) float f32x4;

__device__ __forceinline__ short f2bf(float f) {
    unsigned u = __builtin_bit_cast(unsigned, f);
    u = (u + 0x7fffu + ((u >> 16) & 1u)) >> 16;
    return (short)u;
}

// hardware packed f32->bf16 (RNE), 2 elems per instruction
__device__ __forceinline__ short8 pack8(f32x4 a, f32x4 b) {
    union { unsigned u[4]; short8 s; } r;
    asm("v_cvt_pk_bf16_f32 %0, %1, %2" : "=v"(r.u[0]) : "v"(a[0]), "v"(a[1]));
    asm("v_cvt_pk_bf16_f32 %0, %1, %2" : "=v"(r.u[1]) : "v"(a[2]), "v"(a[3]));
    asm("v_cvt_pk_bf16_f32 %0, %1, %2" : "=v"(r.u[2]) : "v"(b[0]), "v"(b[1]));
    asm("v_cvt_pk_bf16_f32 %0, %1, %2" : "=v"(r.u[3]) : "v"(b[2]), "v"(b[3]));
    return r.s;
}

// ---- prep: W2 -> bf16 fragment-packed (verified layout, unchanged) ----
__global__ void prep_w2f(const float* __restrict__ W, short* __restrict__ w2f) {
    int idx = blockIdx.x * 256 + threadIdx.x;   // 0 .. 262143
    int j    = idx & 7;
    int lane = (idx >> 3) & 63;
    int ni   = (idx >> 9) & 3;
    int ck   = (idx >> 11) & 15;
    int c    = (idx >> 15) & 7;
    int h = c * 64 + ni * 16 + (lane & 15);
    int k = ck * 32 + (lane >> 4) * 8 + j;
    w2f[idx] = f2bf(W[h * (2 * H_) + H_ + k]);
}

// ---- prep: hid_proj[b][h] = hidden[b,:]*W1[h,:] + bias[h] (f32 exact) ----
__global__ void prep_hid(const float* __restrict__ hidden,
                         const float* __restrict__ W,
                         const float* __restrict__ bias,
                         float* __restrict__ hidproj) {
    __shared__ float hrow[H_];
    int b = blockIdx.y;
    int h = blockIdx.x * 128 + threadIdx.x;
    for (int i = threadIdx.x; i < H_; i += 128) hrow[i] = hidden[b * H_ + i];
    __syncthreads();
    const float* wr = W + (size_t)h * (2 * H_);
    float acc = bias[h];
#pragma unroll 4
    for (int k = 0; k < H_; k += 4) {
        acc += hrow[k]     * wr[k];
        acc += hrow[k + 1] * wr[k + 1];
        acc += hrow[k + 2] * wr[k + 2];
        acc += hrow[k + 3] * wr[k + 3];
    }
    hidproj[b * H_ + h] = acc;
}

// ---- finisher: out[b,t] = relu(sp0 + sp1) ----
__global__ void finish(const float* __restrict__ sp, float* __restrict__ out) {
    int i = blockIdx.x * 256 + threadIdx.x;
    out[i] = fmaxf(sp[i] + sp[131072 + i], 0.f);
}

// ---- main: 4-wave blocks, h-split, A-prefetch distance 2 (reg-held) ----
__global__ __launch_bounds__(NTHREADS, 3)
void attn_main(const float* __restrict__ enc,      // [T*B][H] f32
               const float* __restrict__ hidproj,  // [B][H] f32
               const short* __restrict__ w2f,      // frag-packed bf16 W2
               const float* __restrict__ vvec,     // [H]
               float* __restrict__ spart)          // [2][B*T] partial scores
{
    __shared__ __align__(16) short lds_a[2][M_TILE * BK];  // 2 x 8 KB

    const int tid  = threadIdx.x;
    const int lane = tid & 63;
    const int wid  = tid >> 6;
    const int bid  = blockIdx.x;
    const int tau  = ((bid >> 4) << 3) | (bid & 7);   // eta-pair shares XCD
    const int eta  = (bid >> 3) & 1;
    const int t0   = tau * TILE_T;
    const int lo   = lane & 15;
    const int hi4  = lane >> 4;
    const int cblk = eta * 4 + wid;     // col block 0..7

    f32x4 acc[4][4];
#pragma unroll
    for (int i = 0; i < 4; ++i)
#pragma unroll
        for (int j = 0; j < 4; ++j) acc[i][j] = f32x4{0.f, 0.f, 0.f, 0.f};

    const short* wbase = w2f + (size_t)cblk * 32768 + lane * 8;

    const int arow = tid >> 2;
    const int akc  = tid & 3;
    const float* abase = enc + (size_t)(t0 * B_ + arow) * H_ + akc * 16;
    const int aw0 = arow * BK + (((2 * akc)     ^ (arow & 7)) << 3);
    const int aw1 = arow * BK + (((2 * akc + 1) ^ (arow & 7)) << 3);

    // A-prefetch register sets: xP holds A(next), xQ holds A(next+1) alternating
    f32x4 xP0, xP1, xP2, xP3, xQ0, xQ1, xQ2, xQ3;

    // ---- prologue: stage A(0) direct; preload xP = A(1) ----
    {
        f32x4 y0 = *(const f32x4*)(abase);     f32x4 y1 = *(const f32x4*)(abase + 4);
        f32x4 y2 = *(const f32x4*)(abase + 8); f32x4 y3 = *(const f32x4*)(abase + 12);
        const float* a1 = abase + BK;
        xP0 = *(const f32x4*)(a1);      xP1 = *(const f32x4*)(a1 + 4);
        xP2 = *(const f32x4*)(a1 + 8);  xP3 = *(const f32x4*)(a1 + 12);
        *(short8*)&lds_a[0][aw0] = pack8(y0, y1);
        *(short8*)&lds_a[0][aw1] = pack8(y2, y3);
        asm volatile("s_waitcnt lgkmcnt(0)" ::: "memory");
        __builtin_amdgcn_s_barrier();
    }

#define KSUB(AB, S, BQ)                                                           \
    {                                                                             \
        bf16x8 af[4];                                                             \
        _Pragma("unroll")                                                         \
        for (int mi = 0; mi < 4; ++mi) {                                          \
            int r = mi * 16 + lo;                                                 \
            af[mi] = *(const bf16x8*)&AB[r * BK + ((((S) * 4 + hi4) ^ (r & 7)) << 3)]; \
        }                                                                         \
        __builtin_amdgcn_s_setprio(1);                                            \
        _Pragma("unroll")                                                         \
        for (int mi = 0; mi < 4; ++mi)                                            \
            _Pragma("unroll")                                                     \
            for (int ni = 0; ni < 4; ++ni)                                        \
                acc[mi][ni] = __builtin_amdgcn_mfma_f32_16x16x32_bf16(            \
                    af[mi], BQ[ni], acc[mi][ni], 0, 0, 0);                        \
        __builtin_amdgcn_s_setprio(0);                                            \
    }

#pragma unroll 1
    for (int kk = 0; kk < KSTEPS; kk += 2) {
        // ================== even kstep kk: reads lds[0], stages A(kk+1)->lds[1] =====
        {
            const short* __restrict__ ab = &lds_a[0][0];
            short* __restrict__ adst = &lds_a[1][0];
            // prefetch A(kk+2) into xQ (consumed next kstep; ~2 ksteps of cover)
            if (kk + 2 < KSTEPS) {
                const float* asrc = abase + (size_t)(kk + 2) * BK;
                xQ0 = *(const f32x4*)(asrc);      xQ1 = *(const f32x4*)(asrc + 4);
                xQ2 = *(const f32x4*)(asrc + 8);  xQ3 = *(const f32x4*)(asrc + 12);
            }
            bf16x8 b0[4], b1[4];
#pragma unroll
            for (int ni = 0; ni < 4; ++ni) b0[ni] = *(const bf16x8*)(wbase + ((kk * 2 + 0) * 4 + ni) * 512);
#pragma unroll
            for (int ni = 0; ni < 4; ++ni) b1[ni] = *(const bf16x8*)(wbase + ((kk * 2 + 1) * 4 + ni) * 512);

            KSUB(ab, 0, b0)
            *(short8*)&adst[aw0] = pack8(xP0, xP1);   // xP = A(kk+1), loaded long ago
            KSUB(ab, 1, b1)
            *(short8*)&adst[aw1] = pack8(xP2, xP3);

            asm volatile("s_waitcnt lgkmcnt(0)" ::: "memory");
            __builtin_amdgcn_s_barrier();
        }
        // ================== odd kstep kk+1: reads lds[1], stages A(kk+2)->lds[0] ====
        {
            const int k1 = kk + 1;
            const short* __restrict__ ab = &lds_a[1][0];
            short* __restrict__ adst = &lds_a[0][0];
            if (k1 + 2 < KSTEPS) {
                const float* asrc = abase + (size_t)(k1 + 2) * BK;
                xP0 = *(const f32x4*)(asrc);      xP1 = *(const f32x4*)(asrc + 4);
                xP2 = *(const f32x4*)(asrc + 8);  xP3 = *(const f32x4*)(asrc + 12);
            }
            bf16x8 b0[4], b1[4];
#pragma unroll
            for (int ni = 0; ni < 4; ++ni) b0[ni] = *(const bf16x8*)(wbase + ((k1 * 2 + 0) * 4 + ni) * 512);
#pragma unroll
            for (int ni = 0; ni < 4; ++ni) b1[ni] = *(const bf16x8*)(wbase + ((k1 * 2 + 1) * 4 + ni) * 512);

            const bool wr = (k1 + 1) < KSTEPS;   // stage A(kk+2) unless done
            KSUB(ab, 0, b0)
            if (wr) *(short8*)&adst[aw0] = pack8(xQ0, xQ1);
            KSUB(ab, 1, b1)
            if (wr) *(short8*)&adst[aw1] = pack8(xQ2, xQ3);

            asm volatile("s_waitcnt lgkmcnt(0)" ::: "memory");
            __builtin_amdgcn_s_barrier();
        }
    }
#undef KSUB

    // ---- epilogue: energy += hidproj, softmax over b, v-dot partials ----
    {
        float hp[2][4][4];
#pragma unroll
        for (int par = 0; par < 2; ++par)
#pragma unroll
            for (int j = 0; j < 4; ++j) {
                int b = par * 16 + hi4 * 4 + j;
#pragma unroll
                for (int ni = 0; ni < 4; ++ni)
                    hp[par][j][ni] = hidproj[b * H_ + cblk * 64 + ni * 16 + lo];
            }
#pragma unroll
        for (int mi = 0; mi < 4; ++mi)
#pragma unroll
            for (int ni = 0; ni < 4; ++ni)
#pragma unroll
                for (int j = 0; j < 4; ++j)
                    acc[mi][ni][j] += hp[mi & 1][j][ni];
    }

    float vh[4];
#pragma unroll
    for (int ni = 0; ni < 4; ++ni) vh[ni] = vvec[cblk * 64 + ni * 16 + lo];

    float scp[4][4];
#pragma unroll
    for (int tl2 = 0; tl2 < 2; ++tl2) {
        const int m0 = tl2 * 2, m1 = tl2 * 2 + 1;
#pragma unroll
        for (int ni = 0; ni < 4; ++ni) {
            float mx = -1e30f;
#pragma unroll
            for (int j = 0; j < 4; ++j) {
                mx = fmaxf(mx, acc[m0][ni][j]);
                mx = fmaxf(mx, acc[m1][ni][j]);
            }
            mx = fmaxf(mx, __shfl_xor(mx, 16));
            mx = fmaxf(mx, __shfl_xor(mx, 32));
            float e0[4], e1[4];
            float sum = 0.f;
#pragma unroll
            for (int j = 0; j < 4; ++j) {
                e0[j] = __expf(acc[m0][ni][j] - mx);
                e1[j] = __expf(acc[m1][ni][j] - mx);
                sum += e0[j] + e1[j];
            }
            sum += __shfl_xor(sum, 16);
            sum += __shfl_xor(sum, 32);
            float rs = vh[ni] / sum;
#pragma unroll
            for (int j = 0; j < 4; ++j) {
                if (ni == 0) { scp[m0][j] = e0[j] * rs; scp[m1][j] = e1[j] * rs; }
                else         { scp[m0][j] += e0[j] * rs; scp[m1][j] += e1[j] * rs; }
            }
        }
    }

#pragma unroll
    for (int mi = 0; mi < 4; ++mi)
#pragma unroll
        for (int j = 0; j < 4; ++j) {
            float x = scp[mi][j];
            x += __shfl_xor(x, 1);
            x += __shfl_xor(x, 2);
            x += __shfl_xor(x, 4);
            x += __shfl_xor(x, 8);
            scp[mi][j] = x;
        }

    __syncthreads();
    float* red = (float*)&lds_a[0][0];   // 1 KB reuse
    if (lo == 0) {
#pragma unroll
        for (int mi = 0; mi < 4; ++mi)
#pragma unroll
            for (int j = 0; j < 4; ++j)
                red[wid * 64 + mi * 16 + hi4 * 4 + j] = scp[mi][j];
    }
    __syncthreads();
    if (tid < M_TILE) {
        float s = red[tid] + red[64 + tid] + red[128 + tid] + red[192 + tid];
        int b   = tid & 31;
        int tl2 = tid >> 5;
        spart[(size_t)eta * 131072 + (size_t)b * T_ + (t0 + tl2)] = s;
    }
}

extern "C" void kernel_launch(void* const* d_in, const int* in_sizes, int n_in,
                              void* d_out, int out_size, void* d_ws, size_t ws_size,
                              hipStream_t stream) {
    const float* hidden = (const float*)d_in[0];
    const float* enc    = (const float*)d_in[1];
    const float* W      = (const float*)d_in[2];
    const float* bias   = (const float*)d_in[3];
    const float* v      = (const float*)d_in[4];
    float* out = (float*)d_out;

    float* hidproj = (float*)d_ws;                           // 64 KB
    short* w2f     = (short*)((char*)d_ws + 65536);          // 512 KB
    float* spart   = (float*)((char*)d_ws + 65536 + 524288); // 1 MB

    prep_w2f<<<1024, 256, 0, stream>>>(W, w2f);
    prep_hid<<<dim3(4, 32), 128, 0, stream>>>(hidden, W, bias, hidproj);
    attn_main<<<4096, NTHREADS, 0, stream>>>(enc, hidproj, w2f, v, spart);
    finish<<<512, 256, 0, stream>>>(spart, out);
}

// Round 10
// 116.039 us; speedup vs baseline: 1.0473x; 1.0473x over previous
//
#include <hip/hip_runtime.h>
#include <hip/hip_bf16.h>

#define B_ 32
#define T_ 4096
#define H_ 512
#define M_TILE 64    // 2 t x 32 b per block
#define NTHREADS 512 // 8 waves; 2 blocks/CU

typedef __attribute__((ext_vector_type(4))) short short4v;
typedef __attribute__((ext_vector_type(8))) short short8;
typedef __attribute__((ext_vector_type(8))) __bf16 bf16x8;
typedef __attribute__((ext_vector_type(4))) float f32x4;

__device__ __forceinline__ short f2bf(float f) {
    unsigned u = __builtin_bit_cast(unsigned, f);
    u = (u + 0x7fffu + ((u >> 16) & 1u)) >> 16;
    return (short)u;
}

// packed f32->bf16 (RNE): f32x4 -> 4 bf16 (8B)
__device__ __forceinline__ short4v pack4(f32x4 a) {
    union { unsigned u[2]; short4v s; } r;
    asm("v_cvt_pk_bf16_f32 %0, %1, %2" : "=v"(r.u[0]) : "v"(a[0]), "v"(a[1]));
    asm("v_cvt_pk_bf16_f32 %0, %1, %2" : "=v"(r.u[1]) : "v"(a[2]), "v"(a[3]));
    return r.s;
}

// ---- prep: W2 -> bf16 fragment-packed (verified layout R4-R9, unchanged) ----
// w2f[c][ck][ni][lane][j]: h = c*64+ni*16+(lane&15), k = ck*32+(lane>>4)*8+j
__global__ void prep_w2f(const float* __restrict__ W, short* __restrict__ w2f) {
    int idx = blockIdx.x * 256 + threadIdx.x;   // 0 .. 262143
    int j    = idx & 7;
    int lane = (idx >> 3) & 63;
    int ni   = (idx >> 9) & 3;
    int ck   = (idx >> 11) & 15;
    int c    = (idx >> 15) & 7;
    int h = c * 64 + ni * 16 + (lane & 15);
    int k = ck * 32 + (lane >> 4) * 8 + j;
    w2f[idx] = f2bf(W[h * (2 * H_) + H_ + k]);
}

// ---- prep: hid_proj[b][h] = hidden[b,:]*W1[h,:] + bias[h] (f32 exact) ----
__global__ void prep_hid(const float* __restrict__ hidden,
                         const float* __restrict__ W,
                         const float* __restrict__ bias,
                         float* __restrict__ hidproj) {
    __shared__ float hrow[H_];
    int b = blockIdx.y;
    int h = blockIdx.x * 128 + threadIdx.x;
    for (int i = threadIdx.x; i < H_; i += 128) hrow[i] = hidden[b * H_ + i];
    __syncthreads();
    const float* wr = W + (size_t)h * (2 * H_);
    float acc = bias[h];
#pragma unroll 4
    for (int k = 0; k < H_; k += 4) {
        acc += hrow[k]     * wr[k];
        acc += hrow[k + 1] * wr[k + 1];
        acc += hrow[k + 2] * wr[k + 2];
        acc += hrow[k + 3] * wr[k + 3];
    }
    hidproj[b * H_ + h] = acc;
}

// ---- main: full-K tile, stage once, ZERO barriers in compute ----
__global__ __launch_bounds__(NTHREADS, 4)
void attn_main(const float* __restrict__ enc,      // [T*B][H] f32, tile-contiguous
               const float* __restrict__ hidproj,  // [B][H] f32
               const short* __restrict__ w2f,      // frag-packed bf16 W2
               const float* __restrict__ vvec,     // [H]
               float* __restrict__ out)            // [B][T]
{
    __shared__ __align__(16) short lds_a[M_TILE * H_];  // 64 KB bf16, full-K A tile

    const int tid  = threadIdx.x;
    const int lane = tid & 63;
    const int wid  = tid >> 6;          // 0..7 = cblk (64 h each)
    const int lo   = lane & 15;
    const int hi4  = lane >> 4;
    const int t0   = blockIdx.x * 2;    // 2 t per block

    // ================= stage full A tile (128 KB f32 -> 64 KB bf16) ===========
    // flat f32 index (instr i, thread t): i*2048 + t*4  -> fully linear global
    // row = i*4 + (t>>7), col_f32 = (t&127)*4
    // LDS: chunk c = (t&127)>>1 (16B), half = t&1 (8B); store at c^(row&7)
    {
        const float* sp = enc + (size_t)blockIdx.x * (M_TILE * H_) + tid * 4;
        const int th    = tid >> 7;
        const int half  = (tid & 1) * 8;                  // byte
        const int cb    = (tid & 127) >> 1;               // chunk 0..63
        char* lb = (char*)lds_a;
#define ST(I, X) { short4v p = pack4(X); \
        *(short4v*)(lb + ((I)*4 + th) * 1024 + ((cb ^ (((I)*4 + th) & 7)) * 16) + half) = p; }
        f32x4 x0  = *(const f32x4*)(sp +  0 * 2048);
        f32x4 x1  = *(const f32x4*)(sp +  1 * 2048);
        f32x4 x2  = *(const f32x4*)(sp +  2 * 2048);
        f32x4 x3  = *(const f32x4*)(sp +  3 * 2048);
        f32x4 x4  = *(const f32x4*)(sp +  4 * 2048);
        f32x4 x5  = *(const f32x4*)(sp +  5 * 2048);
        f32x4 x6  = *(const f32x4*)(sp +  6 * 2048);
        f32x4 x7  = *(const f32x4*)(sp +  7 * 2048);
        ST(0, x0) ST(1, x1) ST(2, x2) ST(3, x3)
        f32x4 x8  = *(const f32x4*)(sp +  8 * 2048);
        f32x4 x9  = *(const f32x4*)(sp +  9 * 2048);
        f32x4 x10 = *(const f32x4*)(sp + 10 * 2048);
        f32x4 x11 = *(const f32x4*)(sp + 11 * 2048);
        ST(4, x4) ST(5, x5) ST(6, x6) ST(7, x7)
        f32x4 x12 = *(const f32x4*)(sp + 12 * 2048);
        f32x4 x13 = *(const f32x4*)(sp + 13 * 2048);
        f32x4 x14 = *(const f32x4*)(sp + 14 * 2048);
        f32x4 x15 = *(const f32x4*)(sp + 15 * 2048);
        ST(8, x8) ST(9, x9) ST(10, x10) ST(11, x11)
        ST(12, x12) ST(13, x13) ST(14, x14) ST(15, x15)
#undef ST
    }
    __syncthreads();   // the ONLY pre-epilogue barrier

    // ================= compute: 16 half-ksteps, no syncs =====================
    f32x4 acc[4][4];
#pragma unroll
    for (int i = 0; i < 4; ++i)
#pragma unroll
        for (int j = 0; j < 4; ++j) acc[i][j] = f32x4{0.f, 0.f, 0.f, 0.f};

    const short* wbase = w2f + (size_t)wid * 32768 + lane * 8;
    const int xm = lo & 7;   // read-side swizzle mask

    // frag read: row = mi*16+lo, chunk c = s*4 + hi4 (s = kk*2+S), addr = row*512 + (c^xm)*8
#define KSUB(S4, BQ)                                                              \
    {                                                                             \
        bf16x8 af[4];                                                             \
        _Pragma("unroll")                                                         \
        for (int mi = 0; mi < 4; ++mi) {                                          \
            int r = mi * 16 + lo;                                                 \
            af[mi] = *(const bf16x8*)&lds_a[r * 512 + (((S4) + hi4) ^ xm) * 8];   \
        }                                                                         \
        __builtin_amdgcn_s_setprio(1);                                            \
        _Pragma("unroll")                                                         \
        for (int mi = 0; mi < 4; ++mi)                                            \
            _Pragma("unroll")                                                     \
            for (int ni = 0; ni < 4; ++ni)                                        \
                acc[mi][ni] = __builtin_amdgcn_mfma_f32_16x16x32_bf16(            \
                    af[mi], BQ[ni], acc[mi][ni], 0, 0, 0);                        \
        __builtin_amdgcn_s_setprio(0);                                            \
    }

    bf16x8 bqA[4], bqB[4];
#pragma unroll
    for (int ni = 0; ni < 4; ++ni) bqA[ni] = *(const bf16x8*)(wbase + (0 * 4 + ni) * 512);

#pragma unroll 1
    for (int kk = 0; kk < 8; ++kk) {
        const int s0 = kk * 2;
        // prefetch B for half-step s0+1 while computing s0
#pragma unroll
        for (int ni = 0; ni < 4; ++ni)
            bqB[ni] = *(const bf16x8*)(wbase + ((s0 + 1) * 4 + ni) * 512);
        KSUB(s0 * 4, bqA)
        // prefetch B for next kk's first half-step
        if (kk < 7) {
#pragma unroll
            for (int ni = 0; ni < 4; ++ni)
                bqA[ni] = *(const bf16x8*)(wbase + ((s0 + 2) * 4 + ni) * 512);
        }
        KSUB((s0 + 1) * 4, bqB)
    }
#undef KSUB

    // ================= epilogue (R8-verified math, full-h direct out) =========
    {
        float hp[2][4][4];
#pragma unroll
        for (int par = 0; par < 2; ++par)
#pragma unroll
            for (int j = 0; j < 4; ++j) {
                int b = par * 16 + hi4 * 4 + j;
#pragma unroll
                for (int ni = 0; ni < 4; ++ni)
                    hp[par][j][ni] = hidproj[b * H_ + wid * 64 + ni * 16 + lo];
            }
#pragma unroll
        for (int mi = 0; mi < 4; ++mi)
#pragma unroll
            for (int ni = 0; ni < 4; ++ni)
#pragma unroll
                for (int j = 0; j < 4; ++j)
                    acc[mi][ni][j] += hp[mi & 1][j][ni];
    }

    float vh[4];
#pragma unroll
    for (int ni = 0; ni < 4; ++ni) vh[ni] = vvec[wid * 64 + ni * 16 + lo];

    float scp[4][4];
#pragma unroll
    for (int tl2 = 0; tl2 < 2; ++tl2) {
        const int m0 = tl2 * 2, m1 = tl2 * 2 + 1;
#pragma unroll
        for (int ni = 0; ni < 4; ++ni) {
            float mx = -1e30f;
#pragma unroll
            for (int j = 0; j < 4; ++j) {
                mx = fmaxf(mx, acc[m0][ni][j]);
                mx = fmaxf(mx, acc[m1][ni][j]);
            }
            mx = fmaxf(mx, __shfl_xor(mx, 16));
            mx = fmaxf(mx, __shfl_xor(mx, 32));
            float e0[4], e1[4];
            float sum = 0.f;
#pragma unroll
            for (int j = 0; j < 4; ++j) {
                e0[j] = __expf(acc[m0][ni][j] - mx);
                e1[j] = __expf(acc[m1][ni][j] - mx);
                sum += e0[j] + e1[j];
            }
            sum += __shfl_xor(sum, 16);
            sum += __shfl_xor(sum, 32);
            float rs = vh[ni] / sum;  // fold v[h] and 1/denom
#pragma unroll
            for (int j = 0; j < 4; ++j) {
                if (ni == 0) { scp[m0][j] = e0[j] * rs; scp[m1][j] = e1[j] * rs; }
                else         { scp[m0][j] += e0[j] * rs; scp[m1][j] += e1[j] * rs; }
            }
        }
    }

#pragma unroll
    for (int mi = 0; mi < 4; ++mi)
#pragma unroll
        for (int j = 0; j < 4; ++j) {
            float x = scp[mi][j];
            x += __shfl_xor(x, 1);
            x += __shfl_xor(x, 2);
            x += __shfl_xor(x, 4);
            x += __shfl_xor(x, 8);
            scp[mi][j] = x;
        }

    __syncthreads();   // all LDS frag reads done before reuse
    float* red = (float*)&lds_a[0];   // [8][64] = 2 KB
    if (lo == 0) {
#pragma unroll
        for (int mi = 0; mi < 4; ++mi)
#pragma unroll
            for (int j = 0; j < 4; ++j)
                red[wid * 64 + mi * 16 + hi4 * 4 + j] = scp[mi][j];
    }
    __syncthreads();
    if (tid < M_TILE) {
        float s = 0.f;
#pragma unroll
        for (int w = 0; w < 8; ++w) s += red[w * 64 + tid];
        int b   = tid & 31;
        int tl2 = tid >> 5;
        out[(size_t)b * T_ + (t0 + tl2)] = fmaxf(s, 0.f);
    }
}

extern "C" void kernel_launch(void* const* d_in, const int* in_sizes, int n_in,
                              void* d_out, int out_size, void* d_ws, size_t ws_size,
                              hipStream_t stream) {
    const float* hidden = (const float*)d_in[0];
    const float* enc    = (const float*)d_in[1];
    const float* W      = (const float*)d_in[2];
    const float* bias   = (const float*)d_in[3];
    const float* v      = (const float*)d_in[4];
    float* out = (float*)d_out;

    float* hidproj = (float*)d_ws;                    // 64 KB
    short* w2f     = (short*)((char*)d_ws + 65536);   // 512 KB

    prep_w2f<<<1024, 256, 0, stream>>>(W, w2f);
    prep_hid<<<dim3(4, 32), 128, 0, stream>>>(hidden, W, bias, hidproj);
    attn_main<<<T_ * B_ / (M_TILE), NTHREADS, 0, stream>>>(enc, hidproj, w2f, v, out);
}